// Round 7
// baseline (248.633 us; speedup 1.0000x reference)
//
#include <hip/hip_runtime.h>

#define M_DIM 2048
#define K_DIM 4096
#define N_DIM 4096
#define KTILES (K_DIM / 64)

typedef unsigned short u16;
typedef unsigned int u32;
typedef __bf16 bf16x8 __attribute__((ext_vector_type(8)));
typedef float f32x4 __attribute__((ext_vector_type(4)));
typedef float f4 __attribute__((ext_vector_type(4)));
typedef u16 u16x8 __attribute__((ext_vector_type(8)));
typedef u32 u32x4 __attribute__((ext_vector_type(4)));

// fp32 -> bf16 round-to-nearest-even
__device__ __forceinline__ u16 f2bf(float f) {
    unsigned int u = __float_as_uint(f);
    u += 0x7fffu + ((u >> 16) & 1u);
    return (u16)(u >> 16);
}

// pack two fp32 -> (bf16(lo) | bf16(hi)<<16), RNE
__device__ __forceinline__ u32 pack2(float lo, float hi) {
    u32 a = __float_as_uint(lo); a += 0x7fffu + ((a >> 16) & 1u);
    u32 b = __float_as_uint(hi); b += 0x7fffu + ((b >> 16) & 1u);
    return (a >> 16) | (b & 0xffff0000u);
}

// async global->LDS, 16B per lane. LDS dest must be wave-uniform base + lane*16.
__device__ __forceinline__ void load16(const void* g, void* l) {
    __builtin_amdgcn_global_load_lds(
        (__attribute__((address_space(1))) const void*)g,
        (__attribute__((address_space(3))) void*)l,
        16, 0, 0);
}

// ------- prep_t: LDS-free transpose, Bt[n][k] = bf16((mask?W:0)[k][n]) ------
__global__ __launch_bounds__(256) void prep_t(const float* __restrict__ W,
                                              const float* __restrict__ Msk,
                                              u16* __restrict__ Bt) {
    const int t = threadIdx.x;
    const int n0 = (blockIdx.x & 31) * 128;         // 32 n-tiles of 128
    const int k0 = (blockIdx.x >> 5) * 64;          // 64 k-tiles of 64
    const int ko = t & 7;                           // k-octet within tile
    const int ng = t >> 3;                          // n-group (4 cols), 0..31

    const float* Wp = W   + (size_t)(k0 + 8 * ko) * N_DIM + n0 + 4 * ng;
    const float* Mp = Msk + (size_t)(k0 + 8 * ko) * N_DIM + n0 + 4 * ng;

    f4 a[8];
#pragma unroll
    for (int j = 0; j < 8; ++j) {
        f4 wv = *(const f4*)(Wp + (size_t)j * N_DIM);
        f4 mv = *(const f4*)(Mp + (size_t)j * N_DIM);
        a[j][0] = mv[0] != 0.f ? wv[0] : 0.f;
        a[j][1] = mv[1] != 0.f ? wv[1] : 0.f;
        a[j][2] = mv[2] != 0.f ? wv[2] : 0.f;
        a[j][3] = mv[3] != 0.f ? wv[3] : 0.f;
    }

    u16* bp = Bt + (size_t)(n0 + 4 * ng) * K_DIM + k0 + 8 * ko;
#pragma unroll
    for (int i = 0; i < 4; ++i) {                   // n within the float4
        u32x4 o;
        o[0] = pack2(a[0][i], a[1][i]);
        o[1] = pack2(a[2][i], a[3][i]);
        o[2] = pack2(a[4][i], a[5][i]);
        o[3] = pack2(a[6][i], a[7][i]);
        *(u32x4*)(bp + (size_t)i * K_DIM) = o;
    }
}

// ------------------- prep_x: x f32 -> bf16, 16 floats/thread ----------------
__global__ __launch_bounds__(256) void prep_x(const float* __restrict__ x,
                                              u16* __restrict__ xb) {
    const int t = threadIdx.x;
    size_t i = ((size_t)blockIdx.x * 256 + t) * 16;
#pragma unroll
    for (int h = 0; h < 2; ++h) {
        f4 v0 = *(const f4*)(x + i + h * 8);
        f4 v1 = *(const f4*)(x + i + h * 8 + 4);
        u16x8 o;
        o[0] = f2bf(v0[0]); o[1] = f2bf(v0[1]); o[2] = f2bf(v0[2]); o[3] = f2bf(v0[3]);
        o[4] = f2bf(v1[0]); o[5] = f2bf(v1[1]); o[6] = f2bf(v1[2]); o[7] = f2bf(v1[3]);
        *(u16x8*)(xb + i + h * 8) = o;
    }
}

// --- gemm8: 128m x 256n, 2m x 2n x 2k waves, MID-ITERATION barrier loop -----
// R6 dataflow (triple-buffer, k-split waves, XCD swizzle, LDS cross-k reduce
// epilogue) with the barrier rotated to sit BETWEEN frag-read issue and frag
// use, so the 12-ds_read latency is absorbed by the barrier wait and waves
// leave the MFMA clusters straight into the next read-issue (desynchronized,
// spreading LDS pressure). Per K-tile:
//   [issue 12 ds_reads of kt]            (buf kt certified at prev barrier)
//   [vmcnt(0): certifies kt+1's 6 loads, the only vm outstanding, 1 iter old]
//   [s_barrier]
//   [stage A+B0 (kt+2)]                  (readers of buf (kt-1)%3 all lgkm-
//                                         certified before this barrier)
//   [lgkm(4) -> 16 MFMA -> lgkm(0)]      (certify A/B0 reads; then B1)
//   [stage B1..3 (kt+2)] [16 MFMA]       -> next iteration, no barrier
// sched_barrier(0) after every inline-asm wait (rule #18).
__global__ __launch_bounds__(512, 2) void gemm8(const u16* __restrict__ A,   // M x K bf16
                                                const u16* __restrict__ Bt,  // N x K bf16
                                                const float* __restrict__ bias,
                                                float* __restrict__ C) {
    __shared__ __align__(16) u16 As[3][128 * 64];   // 3 x 16 KB
    __shared__ __align__(16) u16 Bs[3][256 * 64];   // 3 x 32 KB

    const int t = threadIdx.x;
    // XCD-aware decode: XCD x owns an 8(bm) x 4(bn) chunk -> 16 MB working set
    const int wgid = blockIdx.x;        // 256 WGs, wgid%8 == XCD [m09]
    const int xcd = wgid & 7, c = wgid >> 3;
    const int bm = (xcd & 1) * 8 + (c & 7);     // M/128 = 16
    const int bn = (xcd >> 1) * 4 + (c >> 3);   // N/256 = 16

    const int srow   = t >> 3;
    const int schunk = (t & 7) ^ (srow & 7);
    const u16* gA = A  + (size_t)(bm * 128 + srow) * K_DIM + schunk * 8;
    const u16* gB = Bt + (size_t)(bn * 256 + srow) * K_DIM + schunk * 8;

    const int lane = t & 63;
    const int wv   = t >> 6;
    const int kh = wv >> 2;             // k-half of every K-tile (0/1)
    const int wq = wv & 3;              // position in 2m x 2n wave grid
    const int mo = (wq >> 1) * 64;      // wave m-origin (0/64)
    const int no = (wq & 1) * 128;      // wave n-origin (0/128)
    const int fr = lane & 15;
    const int q  = lane >> 4;
    const int sw = fr & 7;
    const int colK = (((kh << 2) + q) ^ sw) * 8;

#define SA(buf, kt, j) load16(gA + (size_t)(kt) * 64 + (size_t)(j) * 64 * K_DIM, \
                              (buf) + (j) * 4096 + t * 8)
#define SB(buf, kt, j) load16(gB + (size_t)(kt) * 64 + (size_t)(j) * 64 * K_DIM, \
                              (buf) + (j) * 4096 + t * 8)

    f32x4 acc[4][8] = {};   // [i: m 4x16][j: n 8x16]

    // rotating buffer pointers (register-held; never runtime-indexed)
    u16 *aC = (u16*)As[0], *aN1 = (u16*)As[1], *aN2 = (u16*)As[2];
    u16 *bC = (u16*)Bs[0], *bN1 = (u16*)Bs[1], *bN2 = (u16*)Bs[2];

    // prologue: stage tiles 0 and 1 (12 loads in flight), certify tile 0
    SA(aC, 0, 0);  SA(aC, 0, 1);
    SB(bC, 0, 0);  SB(bC, 0, 1);  SB(bC, 0, 2);  SB(bC, 0, 3);
    SA(aN1, 1, 0); SA(aN1, 1, 1);
    SB(bN1, 1, 0); SB(bN1, 1, 1); SB(bN1, 1, 2); SB(bN1, 1, 3);
    asm volatile("s_waitcnt vmcnt(6)" ::: "memory");
    __builtin_amdgcn_sched_barrier(0);
    __builtin_amdgcn_s_barrier();

    for (int kt = 0; kt < KTILES; ++kt) {
        const int kn = (kt + 2) & (KTILES - 1);   // wrap loads: harmless re-stage
        bf16x8 fA[4], fB0[4], fB1[4];

        // ---- issue ALL fragment reads for tile kt (issue order: A, B0, B1) -
#pragma unroll
        for (int i = 0; i < 4; ++i)
            fA[i] = *(const bf16x8*)(aC + (mo + i * 16 + fr) * 64 + colK);
#pragma unroll
        for (int j = 0; j < 4; ++j)
            fB0[j] = *(const bf16x8*)(bC + (no + j * 16 + fr) * 64 + colK);
#pragma unroll
        for (int j = 0; j < 4; ++j)
            fB1[j] = *(const bf16x8*)(bC + (no + 64 + j * 16 + fr) * 64 + colK);

        // ---- certify tile kt+1 (only 6 vm outstanding, ~1 iter old) -------
        asm volatile("s_waitcnt vmcnt(0)" ::: "memory");
        __builtin_amdgcn_sched_barrier(0);
        __builtin_amdgcn_s_barrier();
        // read latency drains during the barrier wait itself.

        // ---- stage A + B-band0 of tile kt+2 (safe: see header comment) ----
        SA(aN2, kn, 0); SA(aN2, kn, 1); SB(bN2, kn, 0);

        // certify the 8 A/B0 reads (4 B1 reads stay outstanding, DS in-order)
        asm volatile("s_waitcnt lgkmcnt(4)" ::: "memory");
        __builtin_amdgcn_sched_barrier(0);
        __builtin_amdgcn_s_setprio(1);
#pragma unroll
        for (int i = 0; i < 4; ++i)
#pragma unroll
            for (int j = 0; j < 4; ++j)
                acc[i][j] = __builtin_amdgcn_mfma_f32_16x16x32_bf16(
                    fA[i], fB0[j], acc[i][j], 0, 0, 0);
        __builtin_amdgcn_s_setprio(0);
        // certify B1 (covered by the 16-MFMA cluster above)
        asm volatile("s_waitcnt lgkmcnt(0)" ::: "memory");
        __builtin_amdgcn_sched_barrier(0);
        SB(bN2, kn, 1); SB(bN2, kn, 2); SB(bN2, kn, 3);
        __builtin_amdgcn_s_setprio(1);
#pragma unroll
        for (int i = 0; i < 4; ++i)
#pragma unroll
            for (int j = 0; j < 4; ++j)
                acc[i][j + 4] = __builtin_amdgcn_mfma_f32_16x16x32_bf16(
                    fA[i], fB1[j], acc[i][j + 4], 0, 0, 0);
        __builtin_amdgcn_s_setprio(0);
        // no barrier here: waves flow straight into next iteration's reads.

        // rotate buffers: tile T lives in buf[T % 3]
        u16* tmp;
        tmp = aC; aC = aN1; aN1 = aN2; aN2 = tmp;
        tmp = bC; bC = bN1; bN1 = bN2; bN2 = tmp;
    }

    // ---- epilogue: cross-k-half reduction through LDS ----------------------
    asm volatile("s_waitcnt vmcnt(0)" ::: "memory");
    __builtin_amdgcn_s_barrier();

    // 32 KB region per wq: wq 0..2 -> Bs[wq] (32 KB each), wq 3 -> As (48 KB)
    float* red = (wq == 3) ? (float*)As : (float*)Bs[wq];

    if (kh == 1) {
#pragma unroll
        for (int i = 0; i < 4; ++i)
#pragma unroll
            for (int j = 0; j < 8; ++j)
                *(f32x4*)(red + (i * 8 + j) * 256 + lane * 4) = acc[i][j];
    }
    asm volatile("s_waitcnt lgkmcnt(0)" ::: "memory");
    __builtin_amdgcn_s_barrier();

    if (kh == 0) {
        const int rb = q * 4;
#pragma unroll
        for (int i = 0; i < 4; ++i) {
#pragma unroll
            for (int j = 0; j < 8; ++j) {
                f32x4 other = *(const f32x4*)(red + (i * 8 + j) * 256 + lane * 4);
                int n = bn * 256 + no + j * 16 + fr;
                float bv = bias[n];
#pragma unroll
                for (int r = 0; r < 4; ++r) {
                    int m = bm * 128 + mo + i * 16 + rb + r;
                    C[(size_t)m * N_DIM + n] = acc[i][j][r] + other[r] + bv;
                }
            }
        }
    }
#undef SA
#undef SB
}

extern "C" void kernel_launch(void* const* d_in, const int* in_sizes, int n_in,
                              void* d_out, int out_size, void* d_ws, size_t ws_size,
                              hipStream_t stream) {
    const float* x    = (const float*)d_in[0];  // 2048 x 4096
    const float* mask = (const float*)d_in[1];  // 4096 x 4096
    const float* W    = (const float*)d_in[2];  // 4096 x 4096
    const float* bias = (const float*)d_in[3];  // 4096
    float* out = (float*)d_out;                 // 2048 x 4096

    u16* Bt = (u16*)d_ws;                                   // N*K bf16 = 32 MB
    u16* xb = (u16*)d_ws + (size_t)N_DIM * K_DIM;           // M*K bf16 = 16 MB

    prep_t<<<2048, 256, 0, stream>>>(W, mask, Bt);
    prep_x<<<2048, 256, 0, stream>>>(x, xb);
    gemm8<<<256, 512, 0, stream>>>(xb, Bt, bias, out);
}